// Round 4
// baseline (4045.617 us; speedup 1.0000x reference)
//
#include <hip/hip_runtime.h>
#include <hip/hip_bf16.h>

// GraphSAGE forward: N=50000 nodes, E=600000 edges, D=H=128, G=128 graphs.
//   x_pre = rownorm(x)
//   h   = leaky(l2norm(mean_agg(x_pre) @ W1l.T + x_pre @ W1r.T))
//   h1  = leaky([h | x_pre] @ fc1_W.T + fc1_b)
//   h2  = leaky(l2norm(mean_agg(h1) @ W2l.T + h1 @ W2r.T))
//   h3  = leaky([h2 | h1] @ fc2_W.T + fc2_b)
//   out = l2norm(leaky(segpool(h3) @ fc3_W.T + fc3_b))

#define NEG_SLOPE 0.01f
#define L2EPS 1e-12f

// ---------------- preprocess: row-normalize x ----------------
__global__ void k_preprocess(const float* __restrict__ x, float* __restrict__ xp, int N) {
    int node = blockIdx.x * 4 + (threadIdx.x >> 6);
    int lane = threadIdx.x & 63;
    if (node >= N) return;
    float2 v = ((const float2*)x)[(size_t)node * 64 + lane];
    float s = v.x + v.y;
    #pragma unroll
    for (int off = 32; off > 0; off >>= 1) s += __shfl_xor(s, off);
    float rinv = (s == 0.0f) ? 0.0f : 1.0f / s;
    float2 o; o.x = v.x * rinv; o.y = v.y * rinv;
    ((float2*)xp)[(size_t)node * 64 + lane] = o;
}

// ---------------- CSR build ----------------
__global__ void k_deg(const int* __restrict__ ei, int* __restrict__ deg, int E) {
    int e = blockIdx.x * blockDim.x + threadIdx.x;
    if (e >= E) return;
    atomicAdd(&deg[ei[E + e]], 1);
}

// single-block scan, wave-shuffle based: 3 barriers per 1024-chunk
__global__ void k_scan(const int* __restrict__ deg, int* __restrict__ rs,
                       int* __restrict__ cursor, int N) {
    __shared__ int wsum[16];
    __shared__ int carry_s;
    int t = threadIdx.x;
    int lane = t & 63, w = t >> 6;
    if (t == 0) carry_s = 0;
    __syncthreads();
    for (int base = 0; base < N; base += 1024) {
        int i = base + t;
        int v = (i < N) ? deg[i] : 0;
        int s = v;
        #pragma unroll
        for (int off = 1; off < 64; off <<= 1) {
            int u = __shfl_up(s, off);
            if (lane >= off) s += u;
        }
        if (lane == 63) wsum[w] = s;
        __syncthreads();
        if (w == 0) {
            int x = (lane < 16) ? wsum[lane] : 0;
            #pragma unroll
            for (int off = 1; off < 16; off <<= 1) {
                int u = __shfl_up(x, off);
                if (lane >= off) x += u;
            }
            if (lane < 16) wsum[lane] = x;
        }
        __syncthreads();
        int wexcl = (w == 0) ? 0 : wsum[w - 1];
        int excl = carry_s + wexcl + (s - v);
        if (i < N) { rs[i] = excl; cursor[i] = excl; }
        __syncthreads();
        if (t == 0) carry_s += wsum[15];
        __syncthreads();
    }
    if (t == 0) rs[N] = carry_s;
}

__global__ void k_fill(const int* __restrict__ ei, int* __restrict__ cursor,
                       int* __restrict__ csr, int E) {
    int e = blockIdx.x * blockDim.x + threadIdx.x;
    if (e >= E) return;
    int src = ei[e];
    int dst = ei[E + e];
    int pos = atomicAdd(&cursor[dst], 1);
    csr[pos] = src;
}

// ---------------- mean aggregation: 2 edges in flight per wave, float4 ----------------
__global__ void k_agg(const float* __restrict__ feat, const int* __restrict__ csr,
                      const int* __restrict__ rs, float* __restrict__ mean, int N) {
    int node = blockIdx.x * 4 + (threadIdx.x >> 6);
    int lane = threadIdx.x & 63;
    if (node >= N) return;
    int beg = rs[node], end = rs[node + 1];
    int d = end - beg;
    int half = lane >> 5;   // which of 2 concurrent edges
    int sub  = lane & 31;   // float4 index within the row
    const float4* f4 = (const float4*)feat;
    float4 acc = make_float4(0.f, 0.f, 0.f, 0.f);
    #pragma unroll 2
    for (int p = beg + half; p < end; p += 2) {
        int s = csr[p];
        float4 v = f4[(size_t)s * 32 + sub];
        acc.x += v.x; acc.y += v.y; acc.z += v.z; acc.w += v.w;
    }
    acc.x += __shfl_xor(acc.x, 32);
    acc.y += __shfl_xor(acc.y, 32);
    acc.z += __shfl_xor(acc.z, 32);
    acc.w += __shfl_xor(acc.w, 32);
    if (half == 0) {
        float inv = (d > 0) ? (1.0f / (float)d) : 0.0f;
        float4 o = make_float4(acc.x * inv, acc.y * inv, acc.z * inv, acc.w * inv);
        ((float4*)(mean + (size_t)node * 128))[sub] = o;
    }
}

// ---------------- fused dual-input GEMM: out = act([A1|A2] @ [Wa|Wb].T) ----------------
// BM=64, BN=128, K=256 (8 kb of 32), 256 threads (4 waves), thread tile 8x4.
// Double-buffered LDS, one barrier per kb.
#define LDA 68   // 272 B row stride (multiple of 16)
#define LDW 132  // 528 B row stride (multiple of 16)

// W column swizzle (breaks stride-4-float col-read clustering)
__device__ __forceinline__ int wswz(int c) { return c ^ (((c >> 5) & 3) << 2); }

template <bool L2N, bool BIAS>
__global__ __launch_bounds__(256, 3) void k_gemm2(
    const float* __restrict__ A1, const float* __restrict__ A2,
    const float* __restrict__ Wa, int ldwa,
    const float* __restrict__ Wb, int ldwb,
    const float* __restrict__ bias,
    float* __restrict__ out, int N)
{
    __shared__ float As[2][32][LDA];
    __shared__ float Ws[2][32][LDW];
    int t = threadIdx.x;
    int tx = t & 31, ty = t >> 5;       // col group (4 cols), row group (8 rows)
    int i0 = blockIdx.x * 64;

    float acc[8][4];
    #pragma unroll
    for (int j = 0; j < 8; ++j)
        #pragma unroll
        for (int i = 0; i < 4; ++i) acc[j][i] = 0.f;

    // A staging: 8 lanes cover one row's 32-k window (128 B coalesced)
    int a_kc = (t & 7) * 4;   // k offset (4 consecutive k per thread)
    int a_r0 = t >> 3;        // rows a_r0 and a_r0+32
    int a_m  = (a_kc >> 3) & 3;  // swizzle selector (const per thread)
    // W staging: 2 lanes per feature row
    int w_f  = t >> 1;        // 0..127
    int w_kc = (t & 1) * 16;  // 16 consecutive k per thread
    int w_fs = wswz(w_f);

    float4 av[2], wv[4];
    auto load_tile = [&](int kb) {
        const float* Asrc = (kb < 4) ? A1 : A2;
        const float* Wsrc = (kb < 4) ? Wa : Wb;
        int ldw = (kb < 4) ? ldwa : ldwb;
        int kloc = (kb & 3) * 32;
        #pragma unroll
        for (int rr = 0; rr < 2; ++rr) {
            int grow = i0 + a_r0 + rr * 32;
            if (grow < N)
                av[rr] = *(const float4*)(Asrc + (size_t)grow * 128 + kloc + a_kc);
            else
                av[rr] = make_float4(0.f, 0.f, 0.f, 0.f);
        }
        const float* wp = Wsrc + (size_t)w_f * ldw + kloc + w_kc;
        #pragma unroll
        for (int q = 0; q < 4; ++q) wv[q] = *(const float4*)(wp + q * 4);
    };
    auto store_tile = [&](int b) {
        #pragma unroll
        for (int rr = 0; rr < 2; ++rr) {
            int rsw = (a_r0 + rr * 32) ^ (a_m << 3);
            #pragma unroll
            for (int jj = 0; jj < 4; ++jj)
                As[b][a_kc + jj][rsw] = ((const float*)&av[rr])[jj];
        }
        #pragma unroll
        for (int q = 0; q < 4; ++q)
            #pragma unroll
            for (int jj = 0; jj < 4; ++jj)
                Ws[b][w_kc + q * 4 + jj][w_fs] = ((const float*)&wv[q])[jj];
    };

    load_tile(0);
    store_tile(0);

    int wc = wswz(tx * 4);
    for (int kb = 0; kb < 8; ++kb) {
        __syncthreads();   // buf[kb&1] visible; buf[(kb+1)&1] free to overwrite
        if (kb < 7) load_tile(kb + 1);
        int b = kb & 1;
        #pragma unroll
        for (int k = 0; k < 32; ++k) {
            int arow = (ty * 8) ^ ((((k >> 3) & 3)) << 3);
            float4 a0 = *(const float4*)&As[b][k][arow];
            float4 a1 = *(const float4*)&As[b][k][arow + 4];
            float4 w0 = *(const float4*)&Ws[b][k][wc];
            float ar[8] = {a0.x, a0.y, a0.z, a0.w, a1.x, a1.y, a1.z, a1.w};
            float wr[4] = {w0.x, w0.y, w0.z, w0.w};
            #pragma unroll
            for (int j = 0; j < 8; ++j)
                #pragma unroll
                for (int i = 0; i < 4; ++i) acc[j][i] += ar[j] * wr[i];
        }
        if (kb < 7) store_tile((kb + 1) & 1);
    }

    // epilogue
    float scale[8];
    if (L2N) {
        #pragma unroll
        for (int j = 0; j < 8; ++j) {
            float s = acc[j][0]*acc[j][0] + acc[j][1]*acc[j][1]
                    + acc[j][2]*acc[j][2] + acc[j][3]*acc[j][3];
            #pragma unroll
            for (int off = 1; off < 32; off <<= 1) s += __shfl_xor(s, off);
            scale[j] = 1.0f / fmaxf(sqrtf(s), L2EPS);
        }
    }
    float b4[4];
    if (BIAS) {
        #pragma unroll
        for (int i = 0; i < 4; ++i) b4[i] = bias[tx * 4 + i];
    }
    #pragma unroll
    for (int j = 0; j < 8; ++j) {
        int row = i0 + ty * 8 + j;
        if (row >= N) continue;
        float4 v; float* vp = (float*)&v;
        #pragma unroll
        for (int i = 0; i < 4; ++i) {
            float xv = acc[j][i];
            if (L2N) xv *= scale[j];
            if (BIAS) xv += b4[i];
            vp[i] = (xv >= 0.f) ? xv : NEG_SLOPE * xv;
        }
        *(float4*)(out + (size_t)row * 128 + tx * 4) = v;
    }
}

// ---------------- pool: chunked partial sums over sorted batch ----------------
#define POOL_ROWS 128
__global__ void k_pool(const float* __restrict__ h3, const int* __restrict__ batch,
                       float* __restrict__ pooled, int N) {
    int f = threadIdx.x;  // 0..127
    int base = blockIdx.x * POOL_ROWS;
    if (base >= N) return;
    int end = min(base + POOL_ROWS, N);
    float acc = 0.f;
    int cur = batch[base];
    for (int i = base; i < end; ++i) {
        int g = batch[i];
        if (g != cur) {
            atomicAdd(&pooled[cur * 128 + f], acc);
            acc = 0.f; cur = g;
        }
        acc += h3[(size_t)i * 128 + f];
    }
    atomicAdd(&pooled[cur * 128 + f], acc);
}

__global__ void k_fc3(const float* __restrict__ pooled, const float* __restrict__ W,
                      const float* __restrict__ b, float* __restrict__ out) {
    int g = blockIdx.x, f = threadIdx.x;
    __shared__ float prow[128];
    __shared__ float red[128];
    prow[f] = pooled[g * 128 + f];
    __syncthreads();
    float acc = b[f];
    #pragma unroll 8
    for (int k = 0; k < 128; ++k) acc += prow[k] * W[f * 128 + k];
    float v = (acc >= 0.f) ? acc : NEG_SLOPE * acc;
    red[f] = v * v;
    __syncthreads();
    for (int o = 64; o > 0; o >>= 1) {
        if (f < o) red[f] += red[f + o];
        __syncthreads();
    }
    float sc = 1.0f / fmaxf(sqrtf(red[0]), L2EPS);
    out[g * 128 + f] = v * sc;
}

// ---------------- launch ----------------
extern "C" void kernel_launch(void* const* d_in, const int* in_sizes, int n_in,
                              void* d_out, int out_size, void* d_ws, size_t ws_size,
                              hipStream_t stream) {
    const float* x    = (const float*)d_in[0];
    const int*   ei   = (const int*)d_in[1];
    const int*   batch= (const int*)d_in[2];
    const float* W1l  = (const float*)d_in[3];
    const float* W1r  = (const float*)d_in[4];
    const float* W2l  = (const float*)d_in[5];
    const float* W2r  = (const float*)d_in[6];
    const float* fc1W = (const float*)d_in[7];
    const float* fc1b = (const float*)d_in[8];
    const float* fc2W = (const float*)d_in[9];
    const float* fc2b = (const float*)d_in[10];
    const float* fc3W = (const float*)d_in[11];
    const float* fc3b = (const float*)d_in[12];

    int N = in_sizes[0] / 128;
    int E = in_sizes[1] / 2;
    int G = out_size / 128;
    float* out = (float*)d_out;

    char* ws = (char*)d_ws;
    size_t off = 0;
    auto alloc = [&](size_t bytes) -> void* {
        void* p = ws + off;
        off = (off + bytes + 255) & ~(size_t)255;
        return p;
    };
    float* xp     = (float*)alloc((size_t)N * 128 * 4);  // x_pre, later reused as h3
    float* mean   = (float*)alloc((size_t)N * 128 * 4);
    float* h      = (float*)alloc((size_t)N * 128 * 4);  // h, later h2
    float* h1     = (float*)alloc((size_t)N * 128 * 4);
    float* pooled = (float*)alloc((size_t)G * 128 * 4);
    int* deg      = (int*)alloc((size_t)N * 4);
    int* rs       = (int*)alloc((size_t)(N + 1) * 4);
    int* cursor   = (int*)alloc((size_t)N * 4);
    int* csr      = (int*)alloc((size_t)E * 4);
    (void)ws_size; (void)n_in;

    hipMemsetAsync(deg, 0, (size_t)N * 4, stream);
    hipMemsetAsync(pooled, 0, (size_t)G * 128 * 4, stream);

    k_preprocess<<<(N + 3) / 4, 256, 0, stream>>>(x, xp, N);
    k_deg<<<(E + 255) / 256, 256, 0, stream>>>(ei, deg, E);
    k_scan<<<1, 1024, 0, stream>>>(deg, rs, cursor, N);
    k_fill<<<(E + 255) / 256, 256, 0, stream>>>(ei, cursor, csr, E);

    int gb = (N + 63) / 64;
    // conv1 + fc1
    k_agg<<<(N + 3) / 4, 256, 0, stream>>>(xp, csr, rs, mean, N);
    k_gemm2<true, false><<<gb, 256, 0, stream>>>(
        mean, xp, W1l, 128, W1r, 128, nullptr, h, N);
    k_gemm2<false, true><<<gb, 256, 0, stream>>>(
        h, xp, fc1W, 256, fc1W + 128, 256, fc1b, h1, N);

    // conv2 + fc2 (h2 -> h buffer, h3 -> xp buffer)
    k_agg<<<(N + 3) / 4, 256, 0, stream>>>(h1, csr, rs, mean, N);
    k_gemm2<true, false><<<gb, 256, 0, stream>>>(
        mean, h1, W2l, 128, W2r, 128, nullptr, h, N);
    k_gemm2<false, true><<<gb, 256, 0, stream>>>(
        h, h1, fc2W, 256, fc2W + 128, 256, fc2b, xp, N);

    // pool + head
    k_pool<<<(N + POOL_ROWS - 1) / POOL_ROWS, 128, 0, stream>>>(xp, batch, pooled, N);
    k_fc3<<<G, 128, 0, stream>>>(pooled, fc3W, fc3b, out);
}

// Round 6
// 533.974 us; speedup vs baseline: 7.5764x; 7.5764x over previous
//
#include <hip/hip_runtime.h>
#include <hip/hip_bf16.h>

// GraphSAGE forward: N=50000 nodes, E=600000 edges, D=H=128, G=128 graphs.
//   x_pre = rownorm(x)
//   h   = leaky(l2norm(mean_agg(x_pre) @ W1l.T + x_pre @ W1r.T))
//   h1  = leaky([h | x_pre] @ fc1_W.T + fc1_b)
//   h2  = leaky(l2norm(mean_agg(h1) @ W2l.T + h1 @ W2r.T))
//   h3  = leaky([h2 | h1] @ fc2_W.T + fc2_b)
//   out = l2norm(leaky(segpool(h3) @ fc3_W.T + fc3_b))
//
// R4 post-mortem: lambda-captured float4 arrays in the GEMM double-buffer went
// to scratch (3 GB HBM traffic/dispatch, 31 ms first-dispatch scratch alloc).
// This version: R1's measured-good single-buffer GEMM + reg-staged prefetch
// using NAMED float4 scalars only (no arrays, no lambdas), A-tile swizzle.

#define NEG_SLOPE 0.01f
#define L2EPS 1e-12f

// ---------------- preprocess: row-normalize x ----------------
__global__ void k_preprocess(const float* __restrict__ x, float* __restrict__ xp, int N) {
    int node = blockIdx.x * 4 + (threadIdx.x >> 6);
    int lane = threadIdx.x & 63;
    if (node >= N) return;
    float2 v = ((const float2*)x)[(size_t)node * 64 + lane];
    float s = v.x + v.y;
    #pragma unroll
    for (int off = 32; off > 0; off >>= 1) s += __shfl_xor(s, off);
    float rinv = (s == 0.0f) ? 0.0f : 1.0f / s;
    float2 o; o.x = v.x * rinv; o.y = v.y * rinv;
    ((float2*)xp)[(size_t)node * 64 + lane] = o;
}

// ---------------- CSR build ----------------
__global__ void k_deg(const int* __restrict__ ei, int* __restrict__ deg, int E) {
    int e = blockIdx.x * blockDim.x + threadIdx.x;
    if (e >= E) return;
    atomicAdd(&deg[ei[E + e]], 1);
}

// single-block scan, wave-shuffle based: 3 barriers per 1024-chunk
__global__ void k_scan(const int* __restrict__ deg, int* __restrict__ rs,
                       int* __restrict__ cursor, int N) {
    __shared__ int wsum[16];
    __shared__ int carry_s;
    int t = threadIdx.x;
    int lane = t & 63, w = t >> 6;
    if (t == 0) carry_s = 0;
    __syncthreads();
    for (int base = 0; base < N; base += 1024) {
        int i = base + t;
        int v = (i < N) ? deg[i] : 0;
        int s = v;
        #pragma unroll
        for (int off = 1; off < 64; off <<= 1) {
            int u = __shfl_up(s, off);
            if (lane >= off) s += u;
        }
        if (lane == 63) wsum[w] = s;
        __syncthreads();
        if (w == 0) {
            int x = (lane < 16) ? wsum[lane] : 0;
            #pragma unroll
            for (int off = 1; off < 16; off <<= 1) {
                int u = __shfl_up(x, off);
                if (lane >= off) x += u;
            }
            if (lane < 16) wsum[lane] = x;
        }
        __syncthreads();
        int wexcl = (w == 0) ? 0 : wsum[w - 1];
        int excl = carry_s + wexcl + (s - v);
        if (i < N) { rs[i] = excl; cursor[i] = excl; }
        __syncthreads();
        if (t == 0) carry_s += wsum[15];
        __syncthreads();
    }
    if (t == 0) rs[N] = carry_s;
}

__global__ void k_fill(const int* __restrict__ ei, int* __restrict__ cursor,
                       int* __restrict__ csr, int E) {
    int e = blockIdx.x * blockDim.x + threadIdx.x;
    if (e >= E) return;
    int src = ei[e];
    int dst = ei[E + e];
    int pos = atomicAdd(&cursor[dst], 1);
    csr[pos] = src;
}

// ---------------- mean aggregation: 2 edges in flight per wave, float4 ----------------
__global__ void k_agg(const float* __restrict__ feat, const int* __restrict__ csr,
                      const int* __restrict__ rs, float* __restrict__ mean, int N) {
    int node = blockIdx.x * 4 + (threadIdx.x >> 6);
    int lane = threadIdx.x & 63;
    if (node >= N) return;
    int beg = rs[node], end = rs[node + 1];
    int d = end - beg;
    int half = lane >> 5;   // which of 2 concurrent edges
    int sub  = lane & 31;   // float4 index within the row
    const float4* f4 = (const float4*)feat;
    float4 acc = make_float4(0.f, 0.f, 0.f, 0.f);
    #pragma unroll 2
    for (int p = beg + half; p < end; p += 2) {
        int s = csr[p];
        float4 v = f4[(size_t)s * 32 + sub];
        acc.x += v.x; acc.y += v.y; acc.z += v.z; acc.w += v.w;
    }
    acc.x += __shfl_xor(acc.x, 32);
    acc.y += __shfl_xor(acc.y, 32);
    acc.z += __shfl_xor(acc.z, 32);
    acc.w += __shfl_xor(acc.w, 32);
    if (half == 0) {
        float inv = (d > 0) ? (1.0f / (float)d) : 0.0f;
        float4 o = make_float4(acc.x * inv, acc.y * inv, acc.z * inv, acc.w * inv);
        ((float4*)(mean + (size_t)node * 128))[sub] = o;
    }
}

// ---------------- fused dual-input GEMM: out = act([A1|A2] @ [Wa|Wb].T) ----------------
// BM=128, BN=128, K=256 (8 kb of 32), 256 threads, thread tile 8x8.
// Single LDS buffer (R1-proven), reg-staged prefetch with NAMED scalars.
#define LDT 132  // 528 B row stride (multiple of 16)

// column swizzle (involution): spreads stride-8 col reads to 2-way banks
__device__ __forceinline__ int wswz(int c) { return c ^ (((c >> 5) & 3) << 2); }

// load tile kb_ into named staged regs (sa0..sa3 = A row chunk, sw0..sw3 = W row chunk)
#define LOAD_TILE(kb_) do {                                                   \
    const float* Asrc_ = ((kb_) < 4) ? A1 : A2;                               \
    const float* Wsrc_ = ((kb_) < 4) ? Wa : Wb;                               \
    int ldw_  = ((kb_) < 4) ? ldwa : ldwb;                                    \
    int kloc_ = ((kb_) & 3) * 32;                                             \
    int grow_ = i0 + a_r;                                                     \
    if (grow_ < N) {                                                          \
        const float* ap_ = Asrc_ + (size_t)grow_ * 128 + kloc_ + a_kc;        \
        sa0 = *(const float4*)(ap_);      sa1 = *(const float4*)(ap_ + 4);    \
        sa2 = *(const float4*)(ap_ + 8);  sa3 = *(const float4*)(ap_ + 12);   \
    } else {                                                                  \
        sa0 = make_float4(0.f,0.f,0.f,0.f); sa1 = sa0; sa2 = sa0; sa3 = sa0;  \
    }                                                                         \
    const float* wp_ = Wsrc_ + (size_t)a_r * ldw_ + kloc_ + a_kc;             \
    sw0 = *(const float4*)(wp_);      sw1 = *(const float4*)(wp_ + 4);        \
    sw2 = *(const float4*)(wp_ + 8);  sw3 = *(const float4*)(wp_ + 12);       \
} while (0)

#define STORE_TILE() do {                                                     \
    As[a_kc +  0][fsw] = sa0.x; As[a_kc +  1][fsw] = sa0.y;                   \
    As[a_kc +  2][fsw] = sa0.z; As[a_kc +  3][fsw] = sa0.w;                   \
    As[a_kc +  4][fsw] = sa1.x; As[a_kc +  5][fsw] = sa1.y;                   \
    As[a_kc +  6][fsw] = sa1.z; As[a_kc +  7][fsw] = sa1.w;                   \
    As[a_kc +  8][fsw] = sa2.x; As[a_kc +  9][fsw] = sa2.y;                   \
    As[a_kc + 10][fsw] = sa2.z; As[a_kc + 11][fsw] = sa2.w;                   \
    As[a_kc + 12][fsw] = sa3.x; As[a_kc + 13][fsw] = sa3.y;                   \
    As[a_kc + 14][fsw] = sa3.z; As[a_kc + 15][fsw] = sa3.w;                   \
    Ws[a_kc +  0][fsw] = sw0.x; Ws[a_kc +  1][fsw] = sw0.y;                   \
    Ws[a_kc +  2][fsw] = sw0.z; Ws[a_kc +  3][fsw] = sw0.w;                   \
    Ws[a_kc +  4][fsw] = sw1.x; Ws[a_kc +  5][fsw] = sw1.y;                   \
    Ws[a_kc +  6][fsw] = sw1.z; Ws[a_kc +  7][fsw] = sw1.w;                   \
    Ws[a_kc +  8][fsw] = sw2.x; Ws[a_kc +  9][fsw] = sw2.y;                   \
    Ws[a_kc + 10][fsw] = sw2.z; Ws[a_kc + 11][fsw] = sw2.w;                   \
    Ws[a_kc + 12][fsw] = sw3.x; Ws[a_kc + 13][fsw] = sw3.y;                   \
    Ws[a_kc + 14][fsw] = sw3.z; Ws[a_kc + 15][fsw] = sw3.w;                   \
} while (0)

template <bool L2N, bool BIAS>
__global__ __launch_bounds__(256) void k_gemm2(
    const float* __restrict__ A1, const float* __restrict__ A2,
    const float* __restrict__ Wa, int ldwa,
    const float* __restrict__ Wb, int ldwb,
    const float* __restrict__ bias,
    float* __restrict__ out, int N)
{
    __shared__ float As[32][LDT];
    __shared__ float Ws[32][LDT];
    int t = threadIdx.x;
    int tx = t & 15, ty = t >> 4;
    int i0 = blockIdx.x * 128;

    float acc[8][8];
    #pragma unroll
    for (int j = 0; j < 8; ++j)
        #pragma unroll
        for (int i = 0; i < 8; ++i) acc[j][i] = 0.f;

    int a_r  = t >> 1;        // 0..127: row of A tile / feature row of W
    int a_kc = (t & 1) * 16;  // 16 consecutive k per thread
    int fsw = wswz(a_r);      // swizzled LDS column for both tiles

    float4 sa0, sa1, sa2, sa3, sw0, sw1, sw2, sw3;

    LOAD_TILE(0);
    int ac0 = wswz(ty * 8), ac1 = wswz(ty * 8 + 4);
    int wc0 = wswz(tx * 8), wc1 = wswz(tx * 8 + 4);

    for (int kb = 0; kb < 8; ++kb) {
        __syncthreads();   // previous tile fully consumed
        STORE_TILE();
        __syncthreads();
        if (kb < 7) LOAD_TILE(kb + 1);  // latency hides under compute below

        #pragma unroll
        for (int k = 0; k < 32; ++k) {
            float4 a0 = *(const float4*)&As[k][ac0];
            float4 a1 = *(const float4*)&As[k][ac1];
            float4 w0 = *(const float4*)&Ws[k][wc0];
            float4 w1 = *(const float4*)&Ws[k][wc1];
            float ar[8] = {a0.x, a0.y, a0.z, a0.w, a1.x, a1.y, a1.z, a1.w};
            float wr[8] = {w0.x, w0.y, w0.z, w0.w, w1.x, w1.y, w1.z, w1.w};
            #pragma unroll
            for (int j = 0; j < 8; ++j)
                #pragma unroll
                for (int i = 0; i < 8; ++i) acc[j][i] += ar[j] * wr[i];
        }
    }

    // epilogue
    float scale[8];
    if (L2N) {
        #pragma unroll
        for (int j = 0; j < 8; ++j) {
            float s = 0.f;
            #pragma unroll
            for (int i = 0; i < 8; ++i) s += acc[j][i] * acc[j][i];
            #pragma unroll
            for (int off = 1; off < 16; off <<= 1) s += __shfl_xor(s, off);
            scale[j] = 1.0f / fmaxf(sqrtf(s), L2EPS);
        }
    }
    float b8[8];
    if (BIAS) {
        #pragma unroll
        for (int i = 0; i < 8; ++i) b8[i] = bias[tx * 8 + i];
    }
    #pragma unroll
    for (int j = 0; j < 8; ++j) {
        int row = i0 + ty * 8 + j;
        if (row >= N) continue;
        float4 v0, v1; float* vp0 = (float*)&v0; float* vp1 = (float*)&v1;
        #pragma unroll
        for (int i = 0; i < 8; ++i) {
            float xv = acc[j][i];
            if (L2N) xv *= scale[j];
            if (BIAS) xv += b8[i];
            float r = (xv >= 0.f) ? xv : NEG_SLOPE * xv;
            if (i < 4) vp0[i] = r; else vp1[i - 4] = r;
        }
        float* op = out + (size_t)row * 128 + tx * 8;
        *(float4*)op = v0;
        *(float4*)(op + 4) = v1;
    }
}

// ---------------- pool: chunked partial sums over sorted batch ----------------
#define POOL_ROWS 128
__global__ void k_pool(const float* __restrict__ h3, const int* __restrict__ batch,
                       float* __restrict__ pooled, int N) {
    int f = threadIdx.x;  // 0..127
    int base = blockIdx.x * POOL_ROWS;
    if (base >= N) return;
    int end = min(base + POOL_ROWS, N);
    float acc = 0.f;
    int cur = batch[base];
    for (int i = base; i < end; ++i) {
        int g = batch[i];
        if (g != cur) {
            atomicAdd(&pooled[cur * 128 + f], acc);
            acc = 0.f; cur = g;
        }
        acc += h3[(size_t)i * 128 + f];
    }
    atomicAdd(&pooled[cur * 128 + f], acc);
}

__global__ void k_fc3(const float* __restrict__ pooled, const float* __restrict__ W,
                      const float* __restrict__ b, float* __restrict__ out) {
    int g = blockIdx.x, f = threadIdx.x;
    __shared__ float prow[128];
    __shared__ float red[128];
    prow[f] = pooled[g * 128 + f];
    __syncthreads();
    float acc = b[f];
    #pragma unroll 8
    for (int k = 0; k < 128; ++k) acc += prow[k] * W[f * 128 + k];
    float v = (acc >= 0.f) ? acc : NEG_SLOPE * acc;
    red[f] = v * v;
    __syncthreads();
    for (int o = 64; o > 0; o >>= 1) {
        if (f < o) red[f] += red[f + o];
        __syncthreads();
    }
    float sc = 1.0f / fmaxf(sqrtf(red[0]), L2EPS);
    out[g * 128 + f] = v * sc;
}

// ---------------- launch ----------------
extern "C" void kernel_launch(void* const* d_in, const int* in_sizes, int n_in,
                              void* d_out, int out_size, void* d_ws, size_t ws_size,
                              hipStream_t stream) {
    const float* x    = (const float*)d_in[0];
    const int*   ei   = (const int*)d_in[1];
    const int*   batch= (const int*)d_in[2];
    const float* W1l  = (const float*)d_in[3];
    const float* W1r  = (const float*)d_in[4];
    const float* W2l  = (const float*)d_in[5];
    const float* W2r  = (const float*)d_in[6];
    const float* fc1W = (const float*)d_in[7];
    const float* fc1b = (const float*)d_in[8];
    const float* fc2W = (const float*)d_in[9];
    const float* fc2b = (const float*)d_in[10];
    const float* fc3W = (const float*)d_in[11];
    const float* fc3b = (const float*)d_in[12];

    int N = in_sizes[0] / 128;
    int E = in_sizes[1] / 2;
    int G = out_size / 128;
    float* out = (float*)d_out;

    char* ws = (char*)d_ws;
    size_t off = 0;
    auto alloc = [&](size_t bytes) -> void* {
        void* p = ws + off;
        off = (off + bytes + 255) & ~(size_t)255;
        return p;
    };
    float* xp     = (float*)alloc((size_t)N * 128 * 4);  // x_pre, later reused as h3
    float* mean   = (float*)alloc((size_t)N * 128 * 4);
    float* h      = (float*)alloc((size_t)N * 128 * 4);  // h, later h2
    float* h1     = (float*)alloc((size_t)N * 128 * 4);
    float* pooled = (float*)alloc((size_t)G * 128 * 4);
    int* deg      = (int*)alloc((size_t)N * 4);
    int* rs       = (int*)alloc((size_t)(N + 1) * 4);
    int* cursor   = (int*)alloc((size_t)N * 4);
    int* csr      = (int*)alloc((size_t)E * 4);
    (void)ws_size; (void)n_in;

    hipMemsetAsync(deg, 0, (size_t)N * 4, stream);
    hipMemsetAsync(pooled, 0, (size_t)G * 128 * 4, stream);

    k_preprocess<<<(N + 3) / 4, 256, 0, stream>>>(x, xp, N);
    k_deg<<<(E + 255) / 256, 256, 0, stream>>>(ei, deg, E);
    k_scan<<<1, 1024, 0, stream>>>(deg, rs, cursor, N);
    k_fill<<<(E + 255) / 256, 256, 0, stream>>>(ei, cursor, csr, E);

    int gb = (N + 127) / 128;
    // conv1 + fc1
    k_agg<<<(N + 3) / 4, 256, 0, stream>>>(xp, csr, rs, mean, N);
    k_gemm2<true, false><<<gb, 256, 0, stream>>>(
        mean, xp, W1l, 128, W1r, 128, nullptr, h, N);
    k_gemm2<false, true><<<gb, 256, 0, stream>>>(
        h, xp, fc1W, 256, fc1W + 128, 256, fc1b, h1, N);

    // conv2 + fc2 (h2 -> h buffer, h3 -> xp buffer)
    k_agg<<<(N + 3) / 4, 256, 0, stream>>>(h1, csr, rs, mean, N);
    k_gemm2<true, false><<<gb, 256, 0, stream>>>(
        mean, h1, W2l, 128, W2r, 128, nullptr, h, N);
    k_gemm2<false, true><<<gb, 256, 0, stream>>>(
        h, h1, fc2W, 256, fc2W + 128, 256, fc2b, xp, N);

    // pool + head
    k_pool<<<(N + POOL_ROWS - 1) / POOL_ROWS, 128, 0, stream>>>(xp, batch, pooled, N);
    k_fc3<<<G, 128, 0, stream>>>(pooled, fc3W, fc3b, out);
}